// Round 1
// baseline (1288.895 us; speedup 1.0000x reference)
//
#include <hip/hip_runtime.h>
#include <math.h>

#define BM 128
#define BN 128
#define BK 8

__device__ __forceinline__ float wsum64(float v) {
#pragma unroll
  for (int off = 32; off > 0; off >>= 1) v += __shfl_xor(v, off, 64);
  return v;
}

// C[m,n] = sum_k A[m,k]*B[n,k] (+bias, relu, residual-gather variants)
// A row-major [M,K] (or gathered from embed via seq), B row-major [N,K].
template<int GATHER_A, int RELU, int RESID>
__global__ __launch_bounds__(256)
void gemm_tn(const float* __restrict__ A, const int* __restrict__ seq,
             const float* __restrict__ Bm, const float* __restrict__ bias,
             const float* __restrict__ embed, float* __restrict__ C,
             int M, int N, int K)
{
  __shared__ float As[BK][BM];
  __shared__ float Bs[BK][BN];
  const int tid = threadIdx.x;
  const int numN = N / BN;
  const int m0 = (blockIdx.x / numN) * BM;
  const int n0 = (blockIdx.x % numN) * BN;
  const int ty = tid >> 4;       // 0..15
  const int tx = tid & 15;       // 0..15
  const int lr = tid >> 1;       // 0..127 : staged row
  const int lk = (tid & 1) * 4;  // 0 or 4 : staged k offset

  const float* ar = GATHER_A ? (embed + (size_t)seq[m0 + lr] * 512)
                             : (A + (size_t)(m0 + lr) * (size_t)K);
  ar += lk;
  const float* br = Bm + (size_t)(n0 + lr) * (size_t)K + lk;

  float acc[8][8];
#pragma unroll
  for (int i = 0; i < 8; ++i)
#pragma unroll
    for (int j = 0; j < 8; ++j) acc[i][j] = 0.f;

  for (int k0 = 0; k0 < K; k0 += BK) {
    const float4 av = *(const float4*)(ar + k0);
    const float4 bv = *(const float4*)(br + k0);
    As[lk+0][lr] = av.x; As[lk+1][lr] = av.y; As[lk+2][lr] = av.z; As[lk+3][lr] = av.w;
    Bs[lk+0][lr] = bv.x; Bs[lk+1][lr] = bv.y; Bs[lk+2][lr] = bv.z; Bs[lk+3][lr] = bv.w;
    __syncthreads();
#pragma unroll
    for (int k = 0; k < BK; ++k) {
      const float4 a0 = *(const float4*)&As[k][ty*4];
      const float4 a1 = *(const float4*)&As[k][64 + ty*4];
      const float4 b0 = *(const float4*)&Bs[k][tx*4];
      const float4 b1 = *(const float4*)&Bs[k][64 + tx*4];
      const float a[8] = {a0.x,a0.y,a0.z,a0.w,a1.x,a1.y,a1.z,a1.w};
      const float b[8] = {b0.x,b0.y,b0.z,b0.w,b1.x,b1.y,b1.z,b1.w};
#pragma unroll
      for (int i = 0; i < 8; ++i)
#pragma unroll
        for (int j = 0; j < 8; ++j)
          acc[i][j] = fmaf(a[i], b[j], acc[i][j]);
    }
    __syncthreads();
  }

#pragma unroll
  for (int i = 0; i < 8; ++i) {
    const int m = m0 + ((i < 4) ? (ty*4 + i) : (64 + ty*4 + (i - 4)));
    float* crow = C + (size_t)m * (size_t)N;
    const float* hrow = RESID ? (embed + (size_t)seq[m] * 512) : (const float*)0;
#pragma unroll
    for (int jj = 0; jj < 2; ++jj) {
      const int n = n0 + jj*64 + tx*4;
      float4 v;
      v.x = acc[i][jj*4+0] + bias[n+0];
      v.y = acc[i][jj*4+1] + bias[n+1];
      v.z = acc[i][jj*4+2] + bias[n+2];
      v.w = acc[i][jj*4+3] + bias[n+3];
      if (RELU) { v.x = fmaxf(v.x,0.f); v.y = fmaxf(v.y,0.f); v.z = fmaxf(v.z,0.f); v.w = fmaxf(v.w,0.f); }
      if (RESID) { const float4 h4 = *(const float4*)(hrow + n); v.x += h4.x; v.y += h4.y; v.z += h4.z; v.w += h4.w; }
      *(float4*)(crow + n) = v;
    }
  }
}

// in-place LayerNorm, one wave per 512-elem row
__global__ __launch_bounds__(256)
void ln_k(float* __restrict__ x, const float* __restrict__ g,
          const float* __restrict__ bt, int rows)
{
  const int wid = threadIdx.x >> 6, lane = threadIdx.x & 63;
  const int row = blockIdx.x * 4 + wid;
  if (row >= rows) return;
  float* xr = x + (size_t)row * 512;
  const float4 v0 = *(const float4*)(xr + lane*4);
  const float4 v1 = *(const float4*)(xr + 256 + lane*4);
  float s = v0.x+v0.y+v0.z+v0.w + v1.x+v1.y+v1.z+v1.w;
  s = wsum64(s);
  const float mu = s * (1.f/512.f);
  float ss = (v0.x-mu)*(v0.x-mu) + (v0.y-mu)*(v0.y-mu)
           + (v0.z-mu)*(v0.z-mu) + (v0.w-mu)*(v0.w-mu)
           + (v1.x-mu)*(v1.x-mu) + (v1.y-mu)*(v1.y-mu)
           + (v1.z-mu)*(v1.z-mu) + (v1.w-mu)*(v1.w-mu);
  ss = wsum64(ss);
  const float inv = 1.f / sqrtf(ss * (1.f/512.f) + 1e-5f);
  const float4 g0 = *(const float4*)(g + lane*4);
  const float4 g1 = *(const float4*)(g + 256 + lane*4);
  const float4 c0 = *(const float4*)(bt + lane*4);
  const float4 c1 = *(const float4*)(bt + 256 + lane*4);
  float4 o0, o1;
  o0.x = (v0.x-mu)*inv*g0.x + c0.x;  o0.y = (v0.y-mu)*inv*g0.y + c0.y;
  o0.z = (v0.z-mu)*inv*g0.z + c0.z;  o0.w = (v0.w-mu)*inv*g0.w + c0.w;
  o1.x = (v1.x-mu)*inv*g1.x + c1.x;  o1.y = (v1.y-mu)*inv*g1.y + c1.y;
  o1.z = (v1.z-mu)*inv*g1.z + c1.z;  o1.w = (v1.w-mu)*inv*g1.w + c1.w;
  *(float4*)(xr + lane*4) = o0;
  *(float4*)(xr + 256 + lane*4) = o1;
}

// per-candidate score + L2 norm, one wave per row
__global__ __launch_bounds__(256)
void score_k(const float* __restrict__ hidden, const float* __restrict__ wg_w,
             const float* __restrict__ wg_b, float* __restrict__ scores,
             float* __restrict__ norms)
{
  const int wid = threadIdx.x >> 6, lane = threadIdx.x & 63;
  const int rid = blockIdx.x * 4 + wid;
  if (rid >= 32 * 1021) return;
  const int b = rid / 1021;
  const int t = rid - b * 1021;
  const float* hr = hidden + ((size_t)b * 1024 + t) * 512;
  const float4 h0 = *(const float4*)(hr + lane*4);
  const float4 h1 = *(const float4*)(hr + 256 + lane*4);
  const float4 w0 = *(const float4*)(wg_w + lane*4);
  const float4 w1 = *(const float4*)(wg_w + 256 + lane*4);
  float d = h0.x*w0.x + h0.y*w0.y + h0.z*w0.z + h0.w*w0.w
          + h1.x*w1.x + h1.y*w1.y + h1.z*w1.z + h1.w*w1.w;
  float ss = h0.x*h0.x + h0.y*h0.y + h0.z*h0.z + h0.w*h0.w
           + h1.x*h1.x + h1.y*h1.y + h1.z*h1.z + h1.w*h1.w;
  d = wsum64(d); ss = wsum64(ss);
  if (lane == 0) { scores[rid] = d + wg_b[0]; norms[rid] = sqrtf(ss); }
}

// greedy score-ranked selection with cosine dedup; one block per batch row
__global__ __launch_bounds__(256)
void select_k(const float* __restrict__ hidden, const float* __restrict__ scores,
              const float* __restrict__ norms, int* __restrict__ selidx_g,
              int* __restrict__ selcnt_g)
{
  const int b = blockIdx.x;
  const int tid = threadIdx.x;
  const int wid = tid >> 6, lane = tid & 63;
  __shared__ float sc[1024];
  __shared__ float tvec[512];
  __shared__ int   sidx[64];
  __shared__ float snrm[64];
  __shared__ float rv[4]; __shared__ int ri[4];
  __shared__ float wmax[4];
  __shared__ float s_best; __shared__ int s_t; __shared__ int s_accept;

  for (int i = tid; i < 1024; i += 256)
    sc[i] = (i < 1021) ? scores[b*1021 + i] : -INFINITY;
  __syncthreads();

  int count = 0;
  for (int it = 0; it < 1021; ++it) {
    // ---- block argmax with lowest-index tiebreak (stable argsort semantics)
    float bv = -INFINITY; int bi = 1 << 30;
    for (int i = tid; i < 1024; i += 256) {
      const float v = sc[i];
      if (v > bv || (v == bv && i < bi)) { bv = v; bi = i; }
    }
#pragma unroll
    for (int off = 32; off > 0; off >>= 1) {
      const float ov = __shfl_down(bv, off, 64);
      const int   oi = __shfl_down(bi, off, 64);
      if (ov > bv || (ov == bv && oi < bi)) { bv = ov; bi = oi; }
    }
    if (lane == 0) { rv[wid] = bv; ri[wid] = bi; }
    __syncthreads();
    if (tid == 0) {
      float fb = rv[0]; int fi = ri[0];
      for (int w = 1; w < 4; ++w)
        if (rv[w] > fb || (rv[w] == fb && ri[w] < fi)) { fb = rv[w]; fi = ri[w]; }
      s_best = fb; s_t = fi;
      sc[fi] = -INFINITY;  // mark processed
    }
    __syncthreads();
    if (s_best == -INFINITY) break;
    const int t = s_t;
    for (int i = tid; i < 512; i += 256)
      tvec[i] = hidden[((size_t)b*1024 + t)*512 + i];
    __syncthreads();
    const float tn = fmaxf(norms[b*1021 + t], 1e-12f);
    // ---- max cosine sim vs selected set (wave per slot, strided)
    float mymax = -INFINITY;
    for (int m = wid; m < count; m += 4) {
      const float* srow = hidden + ((size_t)b*1024 + sidx[m]) * 512;
      const float4 s0 = *(const float4*)(srow + lane*4);
      const float4 s1 = *(const float4*)(srow + 256 + lane*4);
      const float4 t0 = *(const float4*)(&tvec[lane*4]);
      const float4 t1 = *(const float4*)(&tvec[256 + lane*4]);
      float d = s0.x*t0.x + s0.y*t0.y + s0.z*t0.z + s0.w*t0.w
              + s1.x*t1.x + s1.y*t1.y + s1.z*t1.z + s1.w*t1.w;
      d = wsum64(d);
      const float sim = d / (tn * fmaxf(snrm[m], 1e-12f));
      mymax = fmaxf(mymax, sim);
    }
    if (lane == 0) wmax[wid] = mymax;
    __syncthreads();
    if (tid == 0) {
      const float mx = fmaxf(fmaxf(wmax[0], wmax[1]), fmaxf(wmax[2], wmax[3]));
      const int ok = (count == 0) || (mx <= 0.8f);
      s_accept = ok;
      if (ok) { sidx[count] = t; snrm[count] = norms[b*1021 + t]; }
    }
    __syncthreads();
    if (s_accept) { ++count; if (count == 64) break; }
  }
  __syncthreads();
  if (tid < 64) selidx_g[b*64 + tid] = (tid < count) ? sidx[tid] : 0;
  if (tid == 0) selcnt_g[b] = count;
}

// q = hidden[:, T-2, :] @ q_w^T + q_b ; one wave per output element
__global__ __launch_bounds__(256)
void q_k(const float* __restrict__ hidden, const float* __restrict__ q_w,
         const float* __restrict__ q_b, float* __restrict__ qv)
{
  const int wid = threadIdx.x >> 6, lane = threadIdx.x & 63;
  const int o = blockIdx.x * 4 + wid;   // 0..16383
  const int b = o >> 9, n = o & 511;
  const float* hr = hidden + ((size_t)b*1024 + 1022) * 512;
  const float* wr = q_w + (size_t)n * 512;
  const float4 h0 = *(const float4*)(hr + lane*4);
  const float4 h1 = *(const float4*)(hr + 256 + lane*4);
  const float4 w0 = *(const float4*)(wr + lane*4);
  const float4 w1 = *(const float4*)(wr + 256 + lane*4);
  float d = h0.x*w0.x + h0.y*w0.y + h0.z*w0.z + h0.w*w0.w
          + h1.x*w1.x + h1.y*w1.y + h1.z*w1.z + h1.w*w1.w;
  d = wsum64(d);
  if (lane == 0) qv[o] = d + q_b[n];
}

// masked softmax attention over selected memory; one block per batch
__global__ __launch_bounds__(256)
void attn_k(const float* __restrict__ hidden, const float* __restrict__ qv,
            const int* __restrict__ selidx_g, const int* __restrict__ selcnt_g,
            float* __restrict__ ctx)
{
  const int b = blockIdx.x, tid = threadIdx.x;
  const int wid = tid >> 6, lane = tid & 63;
  __shared__ float qs[512];
  __shared__ int sidx[64];
  __shared__ float sv[64];
  __shared__ float av[64];
  const int count = selcnt_g[b];
  for (int i = tid; i < 512; i += 256) qs[i] = qv[b*512 + i];
  if (tid < 64) sidx[tid] = selidx_g[b*64 + tid];
  __syncthreads();
  for (int m = wid; m < 64; m += 4) {
    float sval = -1e9f;
    if (m < count) {
      const float* hr = hidden + ((size_t)b*1024 + sidx[m]) * 512;
      const float4 a0 = *(const float4*)(hr + lane*4);
      const float4 a1 = *(const float4*)(hr + 256 + lane*4);
      const float4 q0 = *(const float4*)(&qs[lane*4]);
      const float4 q1 = *(const float4*)(&qs[256 + lane*4]);
      float d = a0.x*q0.x + a0.y*q0.y + a0.z*q0.z + a0.w*q0.w
              + a1.x*q1.x + a1.y*q1.y + a1.z*q1.z + a1.w*q1.w;
      d = wsum64(d);
      sval = d;
    }
    if (lane == 0) sv[m] = sval;
  }
  __syncthreads();
  if (tid < 64) {
    const float v = sv[tid];
    float mx = v;
#pragma unroll
    for (int off = 32; off > 0; off >>= 1) mx = fmaxf(mx, __shfl_xor(mx, off, 64));
    const float e = expf(v - mx);
    float ssum = e;
#pragma unroll
    for (int off = 32; off > 0; off >>= 1) ssum += __shfl_xor(ssum, off, 64);
    av[tid] = e / ssum;
  }
  __syncthreads();
  for (int n = tid; n < 512; n += 256) {
    float a = 0.f;
    for (int m = 0; m < count; ++m)
      a += av[m] * hidden[((size_t)b*1024 + sidx[m]) * 512 + n];
    ctx[b*512 + n] = a;
  }
}

// out = ctx @ out_w^T + out_b ; 16 vocab rows x 16 batches per block
__global__ __launch_bounds__(256)
void out_k(const float* __restrict__ ctx, const float* __restrict__ out_w,
           const float* __restrict__ out_b, float* __restrict__ out)
{
  __shared__ float ctxT[512][17];
  const int tid = threadIdx.x;
  const int b0 = (blockIdx.x & 1) * 16;
  const int v0 = (blockIdx.x >> 1) * 16;
  for (int i = tid; i < 16 * 128; i += 256) {
    const int bb = i & 15;
    const int k4 = (i >> 4) * 4;
    const float4 v = *(const float4*)(ctx + (size_t)(b0 + bb)*512 + k4);
    ctxT[k4+0][bb] = v.x; ctxT[k4+1][bb] = v.y;
    ctxT[k4+2][bb] = v.z; ctxT[k4+3][bb] = v.w;
  }
  __syncthreads();
  const int tx = tid & 15;   // batch
  const int ty = tid >> 4;   // vocab row
  const int v = v0 + ty;
  const int bb = b0 + tx;
  const float* wr = out_w + (size_t)v * 512;
  float acc = 0.f;
#pragma unroll 4
  for (int k = 0; k < 512; k += 4) {
    const float4 w4 = *(const float4*)(wr + k);
    acc = fmaf(w4.x, ctxT[k+0][tx], acc);
    acc = fmaf(w4.y, ctxT[k+1][tx], acc);
    acc = fmaf(w4.z, ctxT[k+2][tx], acc);
    acc = fmaf(w4.w, ctxT[k+3][tx], acc);
  }
  out[(size_t)bb * 32000 + v] = acc + out_b[v];
}

extern "C" void kernel_launch(void* const* d_in, const int* in_sizes, int n_in,
                              void* d_out, int out_size, void* d_ws, size_t ws_size,
                              hipStream_t stream)
{
  const int*   seq   = (const int*)d_in[0];
  const float* embed = (const float*)d_in[1];
  const float* w1    = (const float*)d_in[2];
  const float* b1    = (const float*)d_in[3];
  const float* w2    = (const float*)d_in[4];
  const float* b2    = (const float*)d_in[5];
  const float* ln_g  = (const float*)d_in[6];
  const float* ln_b  = (const float*)d_in[7];
  const float* wg_w  = (const float*)d_in[8];
  const float* wg_b  = (const float*)d_in[9];
  const float* q_w   = (const float*)d_in[10];
  const float* q_b   = (const float*)d_in[11];
  const float* out_w = (const float*)d_in[12];
  const float* out_b = (const float*)d_in[13];
  float* out = (float*)d_out;

  char* ws = (char*)d_ws;
  size_t off = 0;
  auto alloc = [&](size_t bytes) {
    void* p = ws + off;
    off += (bytes + 255) & ~(size_t)255;
    return p;
  };
  float* ff1    = (float*)alloc((size_t)32768 * 1024 * 4);  // 134 MB
  float* xbuf   = (float*)alloc((size_t)32768 * 512 * 4);   //  67 MB (x -> hidden in place)
  float* scores = (float*)alloc((size_t)32 * 1021 * 4);
  float* norms  = (float*)alloc((size_t)32 * 1021 * 4);
  int*   selidx = (int*)alloc((size_t)32 * 64 * 4);
  int*   selcnt = (int*)alloc((size_t)32 * 4);
  float* qbuf   = (float*)alloc((size_t)32 * 512 * 4);
  float* ctxb   = (float*)alloc((size_t)32 * 512 * 4);

  // FF1: relu(embed[seq] @ w1^T + b1)  -> ff1   [32768,1024]
  gemm_tn<1,1,0><<<2048, 256, 0, stream>>>(nullptr, seq, w1, b1, embed, ff1,
                                           32768, 1024, 512);
  // FF2: ff1 @ w2^T + b2 + embed[seq]  -> xbuf  [32768,512]
  gemm_tn<0,0,1><<<1024, 256, 0, stream>>>(ff1, seq, w2, b2, embed, xbuf,
                                           32768, 512, 1024);
  // LayerNorm in place -> hidden
  ln_k<<<8192, 256, 0, stream>>>(xbuf, ln_g, ln_b, 32768);
  // scores + norms over candidates [32,1021]
  score_k<<<8168, 256, 0, stream>>>(xbuf, wg_w, wg_b, scores, norms);
  // greedy dedup selection
  select_k<<<32, 256, 0, stream>>>(xbuf, scores, norms, selidx, selcnt);
  // q projection for query row (t = 1022)
  q_k<<<4096, 256, 0, stream>>>(xbuf, q_w, q_b, qbuf);
  // attention over selected memory -> ctx
  attn_k<<<32, 256, 0, stream>>>(xbuf, qbuf, selidx, selcnt, ctxb);
  // final vocab projection
  out_k<<<4000, 256, 0, stream>>>(ctxb, out_w, out_b, out);
}

// Round 2
// 753.488 us; speedup vs baseline: 1.7106x; 1.7106x over previous
//
#include <hip/hip_runtime.h>
#include <math.h>

typedef unsigned short ushort_t;
typedef short bf16x8 __attribute__((ext_vector_type(8)));
typedef unsigned short u16x8 __attribute__((ext_vector_type(8)));
typedef float f32x4 __attribute__((ext_vector_type(4)));

#define PITCH 40   // ushorts per LDS row (32 data + 8 pad) = 80B (16B-aligned, 5 chunks)

__device__ __forceinline__ float wsum64(float v) {
#pragma unroll
  for (int off = 32; off > 0; off >>= 1) v += __shfl_xor(v, off, 64);
  return v;
}

__device__ __forceinline__ ushort_t f2bf(float x) {   // RNE f32->bf16
  unsigned u = __float_as_uint(x);
  return (ushort_t)((u + 0x7fffu + ((u >> 16) & 1u)) >> 16);
}
__device__ __forceinline__ float bf2f(ushort_t h) {
  return __uint_as_float(((unsigned)h) << 16);
}

// ---------------------------------------------------------------------------
// Split-bf16 MFMA GEMM:  C[m,n] = sum_k A[m,k] * B[n,k]  (f32 in, f32 out)
// A: [M,K] f32 (or gathered rows embed[seq[m]] when GATHER)
// B: [N,K] f32 row-major (K-contiguous)
// Each f32 is split hi/lo bf16; product via 3 MFMA terms (ah*bh+al*bh+ah*bl).
// 128x128 tile, BK=32, 4 waves (2x2), per-wave 64x64 via 4x4 16x16x32 frags.
// ---------------------------------------------------------------------------
template<int GATHER, int RELU, int RESID>
__global__ __launch_bounds__(256, 2)
void gemm_mfma(const float* __restrict__ A, const int* __restrict__ seq,
               const float* __restrict__ B, const float* __restrict__ bias,
               const float* __restrict__ resid, float* __restrict__ C,
               int M, int N, int K)
{
  __shared__ ushort_t lds[4 * 128 * PITCH];   // 40 KB
  ushort_t* sAh = lds;
  ushort_t* sAl = lds + 128 * PITCH;
  ushort_t* sBh = lds + 2 * 128 * PITCH;
  ushort_t* sBl = lds + 3 * 128 * PITCH;

  const int tid = threadIdx.x;
  const int numN = N >> 7;
  int bid = blockIdx.x;
  {  // XCD-aware swizzle (grid % 8 == 0 for both instantiations)
    const int chunk = gridDim.x >> 3;
    bid = (bid & 7) * chunk + (bid >> 3);
  }
  const int m0 = (bid / numN) << 7;
  const int n0 = (bid % numN) << 7;

  const int wid = tid >> 6, lane = tid & 63;
  const int wm = wid >> 1, wn = wid & 1;
  const int l16 = lane & 15, lkb = lane >> 4;

  // staging: per buffer 128x32 f32 = 512 chunks of 8 f32; thread handles
  // chunk tid and tid+256.  chunk c: row=c>>2, colf=(c&3)*8
  const int r0 = tid >> 2,            cf0 = (tid & 3) * 8;
  const int r1 = (tid + 256) >> 2,    cf1 = ((tid + 256) & 3) * 8;

  size_t aoff0, aoff1;
  if (GATHER) {
    aoff0 = (size_t)seq[m0 + r0] * (size_t)K + cf0;
    aoff1 = (size_t)seq[m0 + r1] * (size_t)K + cf1;
  } else {
    aoff0 = (size_t)(m0 + r0) * (size_t)K + cf0;
    aoff1 = (size_t)(m0 + r1) * (size_t)K + cf1;
  }
  const size_t boff0 = (size_t)(n0 + r0) * (size_t)K + cf0;
  const size_t boff1 = (size_t)(n0 + r1) * (size_t)K + cf1;
  const int woff0 = r0 * PITCH + cf0;
  const int woff1 = r1 * PITCH + cf1;

  // fragment read byte offsets (ushort index); 80B rows => 16B aligned
  const int ard = (wm * 64 + l16) * PITCH + lkb * 8;
  const int brd = (wn * 64 + l16) * PITCH + lkb * 8;

  f32x4 acc[4][4];
#pragma unroll
  for (int m = 0; m < 4; ++m)
#pragma unroll
    for (int n = 0; n < 4; ++n) acc[m][n] = (f32x4){0.f, 0.f, 0.f, 0.f};

  float4 rA[2][2], rB[2][2];
  auto LOADG = [&](int k0) {
    rA[0][0] = *(const float4*)(A + aoff0 + k0);
    rA[0][1] = *(const float4*)(A + aoff0 + k0 + 4);
    rA[1][0] = *(const float4*)(A + aoff1 + k0);
    rA[1][1] = *(const float4*)(A + aoff1 + k0 + 4);
    rB[0][0] = *(const float4*)(B + boff0 + k0);
    rB[0][1] = *(const float4*)(B + boff0 + k0 + 4);
    rB[1][0] = *(const float4*)(B + boff1 + k0);
    rB[1][1] = *(const float4*)(B + boff1 + k0 + 4);
  };
  auto CVTST = [&](ushort_t* dh, ushort_t* dl, int woff, float4 a, float4 b) {
    u16x8 h, l;
    h[0] = f2bf(a.x); l[0] = f2bf(a.x - bf2f(h[0]));
    h[1] = f2bf(a.y); l[1] = f2bf(a.y - bf2f(h[1]));
    h[2] = f2bf(a.z); l[2] = f2bf(a.z - bf2f(h[2]));
    h[3] = f2bf(a.w); l[3] = f2bf(a.w - bf2f(h[3]));
    h[4] = f2bf(b.x); l[4] = f2bf(b.x - bf2f(h[4]));
    h[5] = f2bf(b.y); l[5] = f2bf(b.y - bf2f(h[5]));
    h[6] = f2bf(b.z); l[6] = f2bf(b.z - bf2f(h[6]));
    h[7] = f2bf(b.w); l[7] = f2bf(b.w - bf2f(h[7]));
    *(u16x8*)(dh + woff) = h;
    *(u16x8*)(dl + woff) = l;
  };

  LOADG(0);
  for (int k0 = 0; k0 < K; k0 += 32) {
    CVTST(sAh, sAl, woff0, rA[0][0], rA[0][1]);
    CVTST(sAh, sAl, woff1, rA[1][0], rA[1][1]);
    CVTST(sBh, sBl, woff0, rB[0][0], rB[0][1]);
    CVTST(sBh, sBl, woff1, rB[1][0], rB[1][1]);
    __syncthreads();
    if (k0 + 32 < K) LOADG(k0 + 32);   // prefetch overlaps MFMA below

    bf16x8 fah[4], fal[4];
#pragma unroll
    for (int m = 0; m < 4; ++m) {
      fah[m] = *(const bf16x8*)(sAh + ard + m * 16 * PITCH);
      fal[m] = *(const bf16x8*)(sAl + ard + m * 16 * PITCH);
    }
#pragma unroll
    for (int n = 0; n < 4; ++n) {
      const bf16x8 fbh = *(const bf16x8*)(sBh + brd + n * 16 * PITCH);
      const bf16x8 fbl = *(const bf16x8*)(sBl + brd + n * 16 * PITCH);
#pragma unroll
      for (int m = 0; m < 4; ++m) {
        acc[m][n] = __builtin_amdgcn_mfma_f32_16x16x32_bf16(fah[m], fbh, acc[m][n], 0, 0, 0);
        acc[m][n] = __builtin_amdgcn_mfma_f32_16x16x32_bf16(fal[m], fbh, acc[m][n], 0, 0, 0);
        acc[m][n] = __builtin_amdgcn_mfma_f32_16x16x32_bf16(fah[m], fbl, acc[m][n], 0, 0, 0);
      }
    }
    __syncthreads();
  }

  // epilogue: C/D frag layout col=lane&15, row=(lane>>4)*4+i
#pragma unroll
  for (int n = 0; n < 4; ++n) {
    const int col = n0 + wn * 64 + n * 16 + l16;
    const float bv = bias[col];
#pragma unroll
    for (int m = 0; m < 4; ++m) {
      const int rbase = m0 + wm * 64 + m * 16 + lkb * 4;
#pragma unroll
      for (int i = 0; i < 4; ++i) {
        const int row = rbase + i;
        float v = acc[m][n][i] + bv;
        if (RELU) v = fmaxf(v, 0.f);
        if (RESID) v += resid[(size_t)seq[row] * 512 + col];
        C[(size_t)row * (size_t)N + col] = v;
      }
    }
  }
}

// in-place LayerNorm, one wave per 512-elem row
__global__ __launch_bounds__(256)
void ln_k(float* __restrict__ x, const float* __restrict__ g,
          const float* __restrict__ bt, int rows)
{
  const int wid = threadIdx.x >> 6, lane = threadIdx.x & 63;
  const int row = blockIdx.x * 4 + wid;
  if (row >= rows) return;
  float* xr = x + (size_t)row * 512;
  const float4 v0 = *(const float4*)(xr + lane*4);
  const float4 v1 = *(const float4*)(xr + 256 + lane*4);
  float s = v0.x+v0.y+v0.z+v0.w + v1.x+v1.y+v1.z+v1.w;
  s = wsum64(s);
  const float mu = s * (1.f/512.f);
  float ss = (v0.x-mu)*(v0.x-mu) + (v0.y-mu)*(v0.y-mu)
           + (v0.z-mu)*(v0.z-mu) + (v0.w-mu)*(v0.w-mu)
           + (v1.x-mu)*(v1.x-mu) + (v1.y-mu)*(v1.y-mu)
           + (v1.z-mu)*(v1.z-mu) + (v1.w-mu)*(v1.w-mu);
  ss = wsum64(ss);
  const float inv = 1.f / sqrtf(ss * (1.f/512.f) + 1e-5f);
  const float4 g0 = *(const float4*)(g + lane*4);
  const float4 g1 = *(const float4*)(g + 256 + lane*4);
  const float4 c0 = *(const float4*)(bt + lane*4);
  const float4 c1 = *(const float4*)(bt + 256 + lane*4);
  float4 o0, o1;
  o0.x = (v0.x-mu)*inv*g0.x + c0.x;  o0.y = (v0.y-mu)*inv*g0.y + c0.y;
  o0.z = (v0.z-mu)*inv*g0.z + c0.z;  o0.w = (v0.w-mu)*inv*g0.w + c0.w;
  o1.x = (v1.x-mu)*inv*g1.x + c1.x;  o1.y = (v1.y-mu)*inv*g1.y + c1.y;
  o1.z = (v1.z-mu)*inv*g1.z + c1.z;  o1.w = (v1.w-mu)*inv*g1.w + c1.w;
  *(float4*)(xr + lane*4) = o0;
  *(float4*)(xr + 256 + lane*4) = o1;
}

// per-candidate score + L2 norm, one wave per row
__global__ __launch_bounds__(256)
void score_k(const float* __restrict__ hidden, const float* __restrict__ wg_w,
             const float* __restrict__ wg_b, float* __restrict__ scores,
             float* __restrict__ norms)
{
  const int wid = threadIdx.x >> 6, lane = threadIdx.x & 63;
  const int rid = blockIdx.x * 4 + wid;
  if (rid >= 32 * 1021) return;
  const int b = rid / 1021;
  const int t = rid - b * 1021;
  const float* hr = hidden + ((size_t)b * 1024 + t) * 512;
  const float4 h0 = *(const float4*)(hr + lane*4);
  const float4 h1 = *(const float4*)(hr + 256 + lane*4);
  const float4 w0 = *(const float4*)(wg_w + lane*4);
  const float4 w1 = *(const float4*)(wg_w + 256 + lane*4);
  float d = h0.x*w0.x + h0.y*w0.y + h0.z*w0.z + h0.w*w0.w
          + h1.x*w1.x + h1.y*w1.y + h1.z*w1.z + h1.w*w1.w;
  float ss = h0.x*h0.x + h0.y*h0.y + h0.z*h0.z + h0.w*h0.w
           + h1.x*h1.x + h1.y*h1.y + h1.z*h1.z + h1.w*h1.w;
  d = wsum64(d); ss = wsum64(ss);
  if (lane == 0) { scores[rid] = d + wg_b[0]; norms[rid] = sqrtf(ss); }
}

// greedy score-ranked selection with cosine dedup; one block per batch row
__global__ __launch_bounds__(256)
void select_k(const float* __restrict__ hidden, const float* __restrict__ scores,
              const float* __restrict__ norms, int* __restrict__ selidx_g,
              int* __restrict__ selcnt_g)
{
  const int b = blockIdx.x;
  const int tid = threadIdx.x;
  const int wid = tid >> 6, lane = tid & 63;
  __shared__ float sc[1024];
  __shared__ float tvec[512];
  __shared__ int   sidx[64];
  __shared__ float snrm[64];
  __shared__ float rv[4]; __shared__ int ri[4];
  __shared__ float wmax[4];
  __shared__ float s_best; __shared__ int s_t; __shared__ int s_accept;

  for (int i = tid; i < 1024; i += 256)
    sc[i] = (i < 1021) ? scores[b*1021 + i] : -INFINITY;
  __syncthreads();

  int count = 0;
  for (int it = 0; it < 1021; ++it) {
    float bv = -INFINITY; int bi = 1 << 30;
    for (int i = tid; i < 1024; i += 256) {
      const float v = sc[i];
      if (v > bv || (v == bv && i < bi)) { bv = v; bi = i; }
    }
#pragma unroll
    for (int off = 32; off > 0; off >>= 1) {
      const float ov = __shfl_down(bv, off, 64);
      const int   oi = __shfl_down(bi, off, 64);
      if (ov > bv || (ov == bv && oi < bi)) { bv = ov; bi = oi; }
    }
    if (lane == 0) { rv[wid] = bv; ri[wid] = bi; }
    __syncthreads();
    if (tid == 0) {
      float fb = rv[0]; int fi = ri[0];
      for (int w = 1; w < 4; ++w)
        if (rv[w] > fb || (rv[w] == fb && ri[w] < fi)) { fb = rv[w]; fi = ri[w]; }
      s_best = fb; s_t = fi;
      sc[fi] = -INFINITY;
    }
    __syncthreads();
    if (s_best == -INFINITY) break;
    const int t = s_t;
    for (int i = tid; i < 512; i += 256)
      tvec[i] = hidden[((size_t)b*1024 + t)*512 + i];
    __syncthreads();
    const float tn = fmaxf(norms[b*1021 + t], 1e-12f);
    float mymax = -INFINITY;
    for (int m = wid; m < count; m += 4) {
      const float* srow = hidden + ((size_t)b*1024 + sidx[m]) * 512;
      const float4 s0 = *(const float4*)(srow + lane*4);
      const float4 s1 = *(const float4*)(srow + 256 + lane*4);
      const float4 t0 = *(const float4*)(&tvec[lane*4]);
      const float4 t1 = *(const float4*)(&tvec[256 + lane*4]);
      float d = s0.x*t0.x + s0.y*t0.y + s0.z*t0.z + s0.w*t0.w
              + s1.x*t1.x + s1.y*t1.y + s1.z*t1.z + s1.w*t1.w;
      d = wsum64(d);
      const float sim = d / (tn * fmaxf(snrm[m], 1e-12f));
      mymax = fmaxf(mymax, sim);
    }
    if (lane == 0) wmax[wid] = mymax;
    __syncthreads();
    if (tid == 0) {
      const float mx = fmaxf(fmaxf(wmax[0], wmax[1]), fmaxf(wmax[2], wmax[3]));
      const int ok = (count == 0) || (mx <= 0.8f);
      s_accept = ok;
      if (ok) { sidx[count] = t; snrm[count] = norms[b*1021 + t]; }
    }
    __syncthreads();
    if (s_accept) { ++count; if (count == 64) break; }
  }
  __syncthreads();
  if (tid < 64) selidx_g[b*64 + tid] = (tid < count) ? sidx[tid] : 0;
  if (tid == 0) selcnt_g[b] = count;
}

// q = hidden[:, T-2, :] @ q_w^T + q_b ; one wave per output element
__global__ __launch_bounds__(256)
void q_k(const float* __restrict__ hidden, const float* __restrict__ q_w,
         const float* __restrict__ q_b, float* __restrict__ qv)
{
  const int wid = threadIdx.x >> 6, lane = threadIdx.x & 63;
  const int o = blockIdx.x * 4 + wid;
  const int b = o >> 9, n = o & 511;
  const float* hr = hidden + ((size_t)b*1024 + 1022) * 512;
  const float* wr = q_w + (size_t)n * 512;
  const float4 h0 = *(const float4*)(hr + lane*4);
  const float4 h1 = *(const float4*)(hr + 256 + lane*4);
  const float4 w0 = *(const float4*)(wr + lane*4);
  const float4 w1 = *(const float4*)(wr + 256 + lane*4);
  float d = h0.x*w0.x + h0.y*w0.y + h0.z*w0.z + h0.w*w0.w
          + h1.x*w1.x + h1.y*w1.y + h1.z*w1.z + h1.w*w1.w;
  d = wsum64(d);
  if (lane == 0) qv[o] = d + q_b[n];
}

// masked softmax attention over selected memory; one block per batch
__global__ __launch_bounds__(256)
void attn_k(const float* __restrict__ hidden, const float* __restrict__ qv,
            const int* __restrict__ selidx_g, const int* __restrict__ selcnt_g,
            float* __restrict__ ctx)
{
  const int b = blockIdx.x, tid = threadIdx.x;
  const int wid = tid >> 6, lane = tid & 63;
  __shared__ float qs[512];
  __shared__ int sidx[64];
  __shared__ float sv[64];
  __shared__ float av[64];
  const int count = selcnt_g[b];
  for (int i = tid; i < 512; i += 256) qs[i] = qv[b*512 + i];
  if (tid < 64) sidx[tid] = selidx_g[b*64 + tid];
  __syncthreads();
  for (int m = wid; m < 64; m += 4) {
    float sval = -1e9f;
    if (m < count) {
      const float* hr = hidden + ((size_t)b*1024 + sidx[m]) * 512;
      const float4 a0 = *(const float4*)(hr + lane*4);
      const float4 a1 = *(const float4*)(hr + 256 + lane*4);
      const float4 q0 = *(const float4*)(&qs[lane*4]);
      const float4 q1 = *(const float4*)(&qs[256 + lane*4]);
      float d = a0.x*q0.x + a0.y*q0.y + a0.z*q0.z + a0.w*q0.w
              + a1.x*q1.x + a1.y*q1.y + a1.z*q1.z + a1.w*q1.w;
      d = wsum64(d);
      sval = d;
    }
    if (lane == 0) sv[m] = sval;
  }
  __syncthreads();
  if (tid < 64) {
    const float v = sv[tid];
    float mx = v;
#pragma unroll
    for (int off = 32; off > 0; off >>= 1) mx = fmaxf(mx, __shfl_xor(mx, off, 64));
    const float e = expf(v - mx);
    float ssum = e;
#pragma unroll
    for (int off = 32; off > 0; off >>= 1) ssum += __shfl_xor(ssum, off, 64);
    av[tid] = e / ssum;
  }
  __syncthreads();
  for (int n = tid; n < 512; n += 256) {
    float a = 0.f;
    for (int m = 0; m < count; ++m)
      a += av[m] * hidden[((size_t)b*1024 + sidx[m]) * 512 + n];
    ctx[b*512 + n] = a;
  }
}

// out = ctx @ out_w^T + out_b ; 16 vocab rows x 16 batches per block
__global__ __launch_bounds__(256)
void out_k(const float* __restrict__ ctx, const float* __restrict__ out_w,
           const float* __restrict__ out_b, float* __restrict__ out)
{
  __shared__ float ctxT[512][17];
  const int tid = threadIdx.x;
  const int b0 = (blockIdx.x & 1) * 16;
  const int v0 = (blockIdx.x >> 1) * 16;
  for (int i = tid; i < 16 * 128; i += 256) {
    const int bb = i & 15;
    const int k4 = (i >> 4) * 4;
    const float4 v = *(const float4*)(ctx + (size_t)(b0 + bb)*512 + k4);
    ctxT[k4+0][bb] = v.x; ctxT[k4+1][bb] = v.y;
    ctxT[k4+2][bb] = v.z; ctxT[k4+3][bb] = v.w;
  }
  __syncthreads();
  const int tx = tid & 15;
  const int ty = tid >> 4;
  const int v = v0 + ty;
  const int bb = b0 + tx;
  const float* wr = out_w + (size_t)v * 512;
  float acc = 0.f;
#pragma unroll 4
  for (int k = 0; k < 512; k += 4) {
    const float4 w4 = *(const float4*)(wr + k);
    acc = fmaf(w4.x, ctxT[k+0][tx], acc);
    acc = fmaf(w4.y, ctxT[k+1][tx], acc);
    acc = fmaf(w4.z, ctxT[k+2][tx], acc);
    acc = fmaf(w4.w, ctxT[k+3][tx], acc);
  }
  out[(size_t)bb * 32000 + v] = acc + out_b[v];
}

extern "C" void kernel_launch(void* const* d_in, const int* in_sizes, int n_in,
                              void* d_out, int out_size, void* d_ws, size_t ws_size,
                              hipStream_t stream)
{
  const int*   seq   = (const int*)d_in[0];
  const float* embed = (const float*)d_in[1];
  const float* w1    = (const float*)d_in[2];
  const float* b1    = (const float*)d_in[3];
  const float* w2    = (const float*)d_in[4];
  const float* b2    = (const float*)d_in[5];
  const float* ln_g  = (const float*)d_in[6];
  const float* ln_b  = (const float*)d_in[7];
  const float* wg_w  = (const float*)d_in[8];
  const float* wg_b  = (const float*)d_in[9];
  const float* q_w   = (const float*)d_in[10];
  const float* q_b   = (const float*)d_in[11];
  const float* out_w = (const float*)d_in[12];
  const float* out_b = (const float*)d_in[13];
  float* out = (float*)d_out;

  char* ws = (char*)d_ws;
  size_t off = 0;
  auto alloc = [&](size_t bytes) {
    void* p = ws + off;
    off += (bytes + 255) & ~(size_t)255;
    return p;
  };
  float* ff1    = (float*)alloc((size_t)32768 * 1024 * 4);  // 134 MB
  float* xbuf   = (float*)alloc((size_t)32768 * 512 * 4);   //  67 MB
  float* scores = (float*)alloc((size_t)32 * 1021 * 4);
  float* norms  = (float*)alloc((size_t)32 * 1021 * 4);
  int*   selidx = (int*)alloc((size_t)32 * 64 * 4);
  int*   selcnt = (int*)alloc((size_t)32 * 4);
  float* qbuf   = (float*)alloc((size_t)32 * 512 * 4);
  float* ctxb   = (float*)alloc((size_t)32 * 512 * 4);

  // FF1: relu(embed[seq] @ w1^T + b1) -> ff1   [32768,1024]  (MFMA split-bf16)
  gemm_mfma<1,1,0><<<2048, 256, 0, stream>>>(embed, seq, w1, b1, nullptr, ff1,
                                             32768, 1024, 512);
  // FF2: ff1 @ w2^T + b2 + embed[seq] -> xbuf  [32768,512]   (MFMA split-bf16)
  gemm_mfma<0,0,1><<<1024, 256, 0, stream>>>(ff1, seq, w2, b2, embed, xbuf,
                                             32768, 512, 1024);
  // LayerNorm in place -> hidden
  ln_k<<<8192, 256, 0, stream>>>(xbuf, ln_g, ln_b, 32768);
  // scores + norms over candidates [32,1021]
  score_k<<<8168, 256, 0, stream>>>(xbuf, wg_w, wg_b, scores, norms);
  // greedy dedup selection
  select_k<<<32, 256, 0, stream>>>(xbuf, scores, norms, selidx, selcnt);
  // q projection for query row (t = 1022)
  q_k<<<4096, 256, 0, stream>>>(xbuf, q_w, q_b, qbuf);
  // attention over selected memory -> ctx
  attn_k<<<32, 256, 0, stream>>>(xbuf, qbuf, selidx, selcnt, ctxb);
  // final vocab projection
  out_k<<<4000, 256, 0, stream>>>(ctxb, out_w, out_b, out);
}

// Round 3
// 476.284 us; speedup vs baseline: 2.7061x; 1.5820x over previous
//
#include <hip/hip_runtime.h>
#include <math.h>

typedef unsigned short ushort_t;
typedef short bf16x8 __attribute__((ext_vector_type(8)));
typedef unsigned short u16x8 __attribute__((ext_vector_type(8)));
typedef float f32x4 __attribute__((ext_vector_type(4)));

#define PITCH 40   // gemm LDS row pitch in ushorts (32 data + 8 pad) = 80B

__device__ __forceinline__ float wsum64(float v) {
#pragma unroll
  for (int off = 32; off > 0; off >>= 1) v += __shfl_xor(v, off, 64);
  return v;
}

__device__ __forceinline__ ushort_t f2bf(float x) {   // RNE f32->bf16
  unsigned u = __float_as_uint(x);
  return (ushort_t)((u + 0x7fffu + ((u >> 16) & 1u)) >> 16);
}
__device__ __forceinline__ float bf2f(ushort_t h) {
  return __uint_as_float(((unsigned)h) << 16);
}

// ---------------------------------------------------------------------------
// Split-bf16 MFMA GEMM:  C[m,n] = sum_k A[m,k] * B[n,k]  (f32 in, f32 out)
// ---------------------------------------------------------------------------
template<int GATHER, int RELU, int RESID>
__global__ __launch_bounds__(256, 2)
void gemm_mfma(const float* __restrict__ A, const int* __restrict__ seq,
               const float* __restrict__ B, const float* __restrict__ bias,
               const float* __restrict__ resid, float* __restrict__ C,
               int M, int N, int K)
{
  __shared__ ushort_t lds[4 * 128 * PITCH];   // 40 KB
  ushort_t* sAh = lds;
  ushort_t* sAl = lds + 128 * PITCH;
  ushort_t* sBh = lds + 2 * 128 * PITCH;
  ushort_t* sBl = lds + 3 * 128 * PITCH;

  const int tid = threadIdx.x;
  const int numN = N >> 7;
  int bid = blockIdx.x;
  {  // XCD-aware swizzle (grid % 8 == 0 for both instantiations)
    const int chunk = gridDim.x >> 3;
    bid = (bid & 7) * chunk + (bid >> 3);
  }
  const int m0 = (bid / numN) << 7;
  const int n0 = (bid % numN) << 7;

  const int wid = tid >> 6, lane = tid & 63;
  const int wm = wid >> 1, wn = wid & 1;
  const int l16 = lane & 15, lkb = lane >> 4;

  const int r0 = tid >> 2,            cf0 = (tid & 3) * 8;
  const int r1 = (tid + 256) >> 2,    cf1 = ((tid + 256) & 3) * 8;

  size_t aoff0, aoff1;
  if (GATHER) {
    aoff0 = (size_t)seq[m0 + r0] * (size_t)K + cf0;
    aoff1 = (size_t)seq[m0 + r1] * (size_t)K + cf1;
  } else {
    aoff0 = (size_t)(m0 + r0) * (size_t)K + cf0;
    aoff1 = (size_t)(m0 + r1) * (size_t)K + cf1;
  }
  const size_t boff0 = (size_t)(n0 + r0) * (size_t)K + cf0;
  const size_t boff1 = (size_t)(n0 + r1) * (size_t)K + cf1;
  const int woff0 = r0 * PITCH + cf0;
  const int woff1 = r1 * PITCH + cf1;

  const int ard = (wm * 64 + l16) * PITCH + lkb * 8;
  const int brd = (wn * 64 + l16) * PITCH + lkb * 8;

  f32x4 acc[4][4];
#pragma unroll
  for (int m = 0; m < 4; ++m)
#pragma unroll
    for (int n = 0; n < 4; ++n) acc[m][n] = (f32x4){0.f, 0.f, 0.f, 0.f};

  float4 rA[2][2], rB[2][2];
  auto LOADG = [&](int k0) {
    rA[0][0] = *(const float4*)(A + aoff0 + k0);
    rA[0][1] = *(const float4*)(A + aoff0 + k0 + 4);
    rA[1][0] = *(const float4*)(A + aoff1 + k0);
    rA[1][1] = *(const float4*)(A + aoff1 + k0 + 4);
    rB[0][0] = *(const float4*)(B + boff0 + k0);
    rB[0][1] = *(const float4*)(B + boff0 + k0 + 4);
    rB[1][0] = *(const float4*)(B + boff1 + k0);
    rB[1][1] = *(const float4*)(B + boff1 + k0 + 4);
  };
  auto CVTST = [&](ushort_t* dh, ushort_t* dl, int woff, float4 a, float4 b) {
    u16x8 h, l;
    h[0] = f2bf(a.x); l[0] = f2bf(a.x - bf2f(h[0]));
    h[1] = f2bf(a.y); l[1] = f2bf(a.y - bf2f(h[1]));
    h[2] = f2bf(a.z); l[2] = f2bf(a.z - bf2f(h[2]));
    h[3] = f2bf(a.w); l[3] = f2bf(a.w - bf2f(h[3]));
    h[4] = f2bf(b.x); l[4] = f2bf(b.x - bf2f(h[4]));
    h[5] = f2bf(b.y); l[5] = f2bf(b.y - bf2f(h[5]));
    h[6] = f2bf(b.z); l[6] = f2bf(b.z - bf2f(h[6]));
    h[7] = f2bf(b.w); l[7] = f2bf(b.w - bf2f(h[7]));
    *(u16x8*)(dh + woff) = h;
    *(u16x8*)(dl + woff) = l;
  };

  LOADG(0);
  for (int k0 = 0; k0 < K; k0 += 32) {
    CVTST(sAh, sAl, woff0, rA[0][0], rA[0][1]);
    CVTST(sAh, sAl, woff1, rA[1][0], rA[1][1]);
    CVTST(sBh, sBl, woff0, rB[0][0], rB[0][1]);
    CVTST(sBh, sBl, woff1, rB[1][0], rB[1][1]);
    __syncthreads();
    if (k0 + 32 < K) LOADG(k0 + 32);

    bf16x8 fah[4], fal[4];
#pragma unroll
    for (int m = 0; m < 4; ++m) {
      fah[m] = *(const bf16x8*)(sAh + ard + m * 16 * PITCH);
      fal[m] = *(const bf16x8*)(sAl + ard + m * 16 * PITCH);
    }
#pragma unroll
    for (int n = 0; n < 4; ++n) {
      const bf16x8 fbh = *(const bf16x8*)(sBh + brd + n * 16 * PITCH);
      const bf16x8 fbl = *(const bf16x8*)(sBl + brd + n * 16 * PITCH);
#pragma unroll
      for (int m = 0; m < 4; ++m) {
        acc[m][n] = __builtin_amdgcn_mfma_f32_16x16x32_bf16(fah[m], fbh, acc[m][n], 0, 0, 0);
        acc[m][n] = __builtin_amdgcn_mfma_f32_16x16x32_bf16(fal[m], fbh, acc[m][n], 0, 0, 0);
        acc[m][n] = __builtin_amdgcn_mfma_f32_16x16x32_bf16(fah[m], fbl, acc[m][n], 0, 0, 0);
      }
    }
    __syncthreads();
  }

#pragma unroll
  for (int n = 0; n < 4; ++n) {
    const int col = n0 + wn * 64 + n * 16 + l16;
    const float bv = bias[col];
#pragma unroll
    for (int m = 0; m < 4; ++m) {
      const int rbase = m0 + wm * 64 + m * 16 + lkb * 4;
#pragma unroll
      for (int i = 0; i < 4; ++i) {
        const int row = rbase + i;
        float v = acc[m][n][i] + bv;
        if (RELU) v = fmaxf(v, 0.f);
        if (RESID) v += resid[(size_t)seq[row] * 512 + col];
        C[(size_t)row * (size_t)N + col] = v;
      }
    }
  }
}

// in-place LayerNorm, one wave per 512-elem row
__global__ __launch_bounds__(256)
void ln_k(float* __restrict__ x, const float* __restrict__ g,
          const float* __restrict__ bt, int rows)
{
  const int wid = threadIdx.x >> 6, lane = threadIdx.x & 63;
  const int row = blockIdx.x * 4 + wid;
  if (row >= rows) return;
  float* xr = x + (size_t)row * 512;
  const float4 v0 = *(const float4*)(xr + lane*4);
  const float4 v1 = *(const float4*)(xr + 256 + lane*4);
  float s = v0.x+v0.y+v0.z+v0.w + v1.x+v1.y+v1.z+v1.w;
  s = wsum64(s);
  const float mu = s * (1.f/512.f);
  float ss = (v0.x-mu)*(v0.x-mu) + (v0.y-mu)*(v0.y-mu)
           + (v0.z-mu)*(v0.z-mu) + (v0.w-mu)*(v0.w-mu)
           + (v1.x-mu)*(v1.x-mu) + (v1.y-mu)*(v1.y-mu)
           + (v1.z-mu)*(v1.z-mu) + (v1.w-mu)*(v1.w-mu);
  ss = wsum64(ss);
  const float inv = 1.f / sqrtf(ss * (1.f/512.f) + 1e-5f);
  const float4 g0 = *(const float4*)(g + lane*4);
  const float4 g1 = *(const float4*)(g + 256 + lane*4);
  const float4 c0 = *(const float4*)(bt + lane*4);
  const float4 c1 = *(const float4*)(bt + 256 + lane*4);
  float4 o0, o1;
  o0.x = (v0.x-mu)*inv*g0.x + c0.x;  o0.y = (v0.y-mu)*inv*g0.y + c0.y;
  o0.z = (v0.z-mu)*inv*g0.z + c0.z;  o0.w = (v0.w-mu)*inv*g0.w + c0.w;
  o1.x = (v1.x-mu)*inv*g1.x + c1.x;  o1.y = (v1.y-mu)*inv*g1.y + c1.y;
  o1.z = (v1.z-mu)*inv*g1.z + c1.z;  o1.w = (v1.w-mu)*inv*g1.w + c1.w;
  *(float4*)(xr + lane*4) = o0;
  *(float4*)(xr + 256 + lane*4) = o1;
}

// per-candidate score + L2 norm, one wave per row
__global__ __launch_bounds__(256)
void score_k(const float* __restrict__ hidden, const float* __restrict__ wg_w,
             const float* __restrict__ wg_b, float* __restrict__ scores,
             float* __restrict__ norms)
{
  const int wid = threadIdx.x >> 6, lane = threadIdx.x & 63;
  const int rid = blockIdx.x * 4 + wid;
  if (rid >= 32 * 1021) return;
  const int b = rid / 1021;
  const int t = rid - b * 1021;
  const float* hr = hidden + ((size_t)b * 1024 + t) * 512;
  const float4 h0 = *(const float4*)(hr + lane*4);
  const float4 h1 = *(const float4*)(hr + 256 + lane*4);
  const float4 w0 = *(const float4*)(wg_w + lane*4);
  const float4 w1 = *(const float4*)(wg_w + 256 + lane*4);
  float d = h0.x*w0.x + h0.y*w0.y + h0.z*w0.z + h0.w*w0.w
          + h1.x*w1.x + h1.y*w1.y + h1.z*w1.z + h1.w*w1.w;
  float ss = h0.x*h0.x + h0.y*h0.y + h0.z*h0.z + h0.w*h0.w
           + h1.x*h1.x + h1.y*h1.y + h1.z*h1.z + h1.w*h1.w;
  d = wsum64(d); ss = wsum64(ss);
  if (lane == 0) { scores[rid] = d + wg_b[0]; norms[rid] = sqrtf(ss); }
}

// ---------------------------------------------------------------------------
// Greedy score-ranked selection with cosine dedup; one block per batch row.
// Phase 1: bitonic argsort (desc score, asc idx) of 1021 scores.
// Phase 2: chunks of 64 sorted candidates; normalized-bf16 rows in LDS;
//          sims via MFMA (chunk x {selected ∪ chunk}); serial resolve on the
//          precomputed 64x128 sim matrix (wave 0).
// ---------------------------------------------------------------------------
__global__ __launch_bounds__(256, 1)
void select_k(const float* __restrict__ hidden, const float* __restrict__ scores,
              const float* __restrict__ norms, int* __restrict__ selidx_g,
              int* __restrict__ selcnt_g)
{
  // rows 0..63 = selected, rows 64..127 = current chunk; pitch 520 u16 (1040B)
  __shared__ __align__(16) ushort_t allH[128 * 520];     // 133120 B (keys alias)
  __shared__ ushort_t simS[64 * 128];                    // bf16 sims, 16 KB
  __shared__ ushort_t sortedIdx[1024];
  __shared__ ushort_t selT[64];
  __shared__ ushort_t newPos[64];
  __shared__ int s_count, s_nacc;

  const int b = blockIdx.x, tid = threadIdx.x;
  const int wid = tid >> 6, lane = tid & 63;
  const int l16 = lane & 15, lkb = lane >> 4;

  // ---- phase 1: bitonic argsort by (-score, idx), stable
  unsigned long long* keys = (unsigned long long*)allH;
  for (int i = tid; i < 1024; i += 256) {
    const float s = (i < 1021) ? scores[b * 1021 + i] : -INFINITY;
    const unsigned u = __float_as_uint(s);
    const unsigned ms = (u & 0x80000000u) ? ~u : (u | 0x80000000u);
    keys[i] = ((unsigned long long)(~ms) << 32) | (unsigned)i;
  }
  __syncthreads();
  for (int k = 2; k <= 1024; k <<= 1) {
    for (int j = k >> 1; j > 0; j >>= 1) {
      for (int i = tid; i < 1024; i += 256) {
        const int ixj = i ^ j;
        if (ixj > i) {
          const unsigned long long a = keys[i], c = keys[ixj];
          const bool up = ((i & k) == 0);
          if ((a > c) == up) { keys[i] = c; keys[ixj] = a; }  // keys unique
        }
      }
      __syncthreads();
    }
  }
  for (int i = tid; i < 1024; i += 256)
    sortedIdx[i] = (ushort_t)(keys[i] & 0xffffu);
  if (tid == 0) s_count = 0;
  __syncthreads();   // keys dead; allH reusable

  // ---- phase 2: chunked greedy NMS
  int p = 0;
  while (true) {
    const int count = s_count;          // uniform (barrier before each read)
    if (count >= 64 || p >= 1021) break;
    const int C = min(64, 1021 - p);

    // stage chunk rows (normalized bf16) into allH rows 64..64+C
    {
      const int r = tid >> 2;               // 0..63
      const int seg = (tid & 3) * 128;      // 0/128/256/384
      if (r < C) {
        const int t = sortedIdx[p + r];
        const float rn = 1.f / fmaxf(norms[b * 1021 + t], 1e-12f);
        const float* src = hidden + ((size_t)b * 1024 + t) * 512 + seg;
        ushort_t* dst = allH + (64 + r) * 520 + seg;
#pragma unroll
        for (int u0 = 0; u0 < 128; u0 += 8) {
          const float4 x = *(const float4*)(src + u0);
          const float4 y = *(const float4*)(src + u0 + 4);
          u16x8 o;
          o[0] = f2bf(x.x * rn); o[1] = f2bf(x.y * rn);
          o[2] = f2bf(x.z * rn); o[3] = f2bf(x.w * rn);
          o[4] = f2bf(y.x * rn); o[5] = f2bf(y.y * rn);
          o[6] = f2bf(y.z * rn); o[7] = f2bf(y.w * rn);
          *(u16x8*)(dst + u0) = o;
        }
      }
    }
    __syncthreads();

    // sims: chunk rows (A) x all 128 rows (B) -> simS[64][128] bf16
    {
      f32x4 acc[8];
#pragma unroll
      for (int t = 0; t < 8; ++t) acc[t] = (f32x4){0.f, 0.f, 0.f, 0.f};
      const ushort_t* Abase = allH + (64 + (wid << 4) + l16) * 520;
#pragma unroll
      for (int ks = 0; ks < 16; ++ks) {
        const bf16x8 a = *(const bf16x8*)(Abase + ks * 32 + lkb * 8);
#pragma unroll
        for (int t = 0; t < 8; ++t) {
          const bf16x8 bb = *(const bf16x8*)(allH + ((t << 4) + l16) * 520 + ks * 32 + lkb * 8);
          acc[t] = __builtin_amdgcn_mfma_f32_16x16x32_bf16(a, bb, acc[t], 0, 0, 0);
        }
      }
#pragma unroll
      for (int t = 0; t < 8; ++t)
#pragma unroll
        for (int ii = 0; ii < 4; ++ii) {
          const int ri = (wid << 4) + lkb * 4 + ii;       // chunk-relative row
          simS[ri * 128 + (t << 4) + l16] = f2bf(acc[t][ii]);
        }
    }
    __syncthreads();

    // serial resolve on wave 0 (no barriers inside)
    if (wid == 0) {
      unsigned long long accMask = 0ull;
      int nacc = 0;
      for (int i = 0; i < C; ++i) {
        float v = -INFINITY;
        if (lane < count) v = bf2f(simS[i * 128 + lane]);
        if ((accMask >> lane) & 1ull) v = fmaxf(v, bf2f(simS[i * 128 + 64 + lane]));
#pragma unroll
        for (int off = 32; off > 0; off >>= 1) v = fmaxf(v, __shfl_xor(v, off, 64));
        const int total = count + nacc;
        const bool ok = (total == 0) || (v <= 0.8f);
        if (total < 64 && ok) {
          if (lane == 0) { selT[total] = sortedIdx[p + i]; newPos[nacc] = (ushort_t)i; }
          accMask |= (1ull << i);
          ++nacc;
          if (total + 1 == 64) break;
        }
      }
      if (lane == 0) { s_nacc = nacc; s_count = count + nacc; }
    }
    __syncthreads();

    // copy accepted chunk rows into selected region (rows count..count+nacc)
    {
      const int nacc = s_nacc;
      for (int a = wid; a < nacc; a += 4) {
        const int srcrow = 64 + (int)newPos[a];
        const int dstrow = count + a;
        const u16x8 val = *(const u16x8*)(allH + srcrow * 520 + lane * 8);
        *(u16x8*)(allH + dstrow * 520 + lane * 8) = val;
      }
    }
    p += C;
    __syncthreads();
  }

  __syncthreads();
  if (tid < 64) selidx_g[b * 64 + tid] = (tid < s_count) ? (int)selT[tid] : 0;
  if (tid == 0) selcnt_g[b] = s_count;
}

// q = hidden[:, T-2, :] @ q_w^T + q_b ; one wave per output element
__global__ __launch_bounds__(256)
void q_k(const float* __restrict__ hidden, const float* __restrict__ q_w,
         const float* __restrict__ q_b, float* __restrict__ qv)
{
  const int wid = threadIdx.x >> 6, lane = threadIdx.x & 63;
  const int o = blockIdx.x * 4 + wid;
  const int b = o >> 9, n = o & 511;
  const float* hr = hidden + ((size_t)b*1024 + 1022) * 512;
  const float* wr = q_w + (size_t)n * 512;
  const float4 h0 = *(const float4*)(hr + lane*4);
  const float4 h1 = *(const float4*)(hr + 256 + lane*4);
  const float4 w0 = *(const float4*)(wr + lane*4);
  const float4 w1 = *(const float4*)(wr + 256 + lane*4);
  float d = h0.x*w0.x + h0.y*w0.y + h0.z*w0.z + h0.w*w0.w
          + h1.x*w1.x + h1.y*w1.y + h1.z*w1.z + h1.w*w1.w;
  d = wsum64(d);
  if (lane == 0) qv[o] = d + q_b[n];
}

// masked softmax attention over selected memory; one block per batch
__global__ __launch_bounds__(256)
void attn_k(const float* __restrict__ hidden, const float* __restrict__ qv,
            const int* __restrict__ selidx_g, const int* __restrict__ selcnt_g,
            float* __restrict__ ctx)
{
  const int b = blockIdx.x, tid = threadIdx.x;
  const int wid = tid >> 6, lane = tid & 63;
  __shared__ float qs[512];
  __shared__ int sidx[64];
  __shared__ float sv[64];
  __shared__ float av[64];
  const int count = selcnt_g[b];
  for (int i = tid; i < 512; i += 256) qs[i] = qv[b*512 + i];
  if (tid < 64) sidx[tid] = selidx_g[b*64 + tid];
  __syncthreads();
  for (int m = wid; m < 64; m += 4) {
    float sval = -1e9f;
    if (m < count) {
      const float* hr = hidden + ((size_t)b*1024 + sidx[m]) * 512;
      const float4 a0 = *(const float4*)(hr + lane*4);
      const float4 a1 = *(const float4*)(hr + 256 + lane*4);
      const float4 q0 = *(const float4*)(&qs[lane*4]);
      const float4 q1 = *(const float4*)(&qs[256 + lane*4]);
      float d = a0.x*q0.x + a0.y*q0.y + a0.z*q0.z + a0.w*q0.w
              + a1.x*q1.x + a1.y*q1.y + a1.z*q1.z + a1.w*q1.w;
      d = wsum64(d);
      sval = d;
    }
    if (lane == 0) sv[m] = sval;
  }
  __syncthreads();
  if (tid < 64) {
    const float v = sv[tid];
    float mx = v;
#pragma unroll
    for (int off = 32; off > 0; off >>= 1) mx = fmaxf(mx, __shfl_xor(mx, off, 64));
    const float e = expf(v - mx);
    float ssum = e;
#pragma unroll
    for (int off = 32; off > 0; off >>= 1) ssum += __shfl_xor(ssum, off, 64);
    av[tid] = e / ssum;
  }
  __syncthreads();
  for (int n = tid; n < 512; n += 256) {
    float a = 0.f;
    for (int m = 0; m < count; ++m)
      a += av[m] * hidden[((size_t)b*1024 + sidx[m]) * 512 + n];
    ctx[b*512 + n] = a;
  }
}

// out = ctx @ out_w^T + out_b ; 16 vocab rows x 16 batches per block
__global__ __launch_bounds__(256)
void out_k(const float* __restrict__ ctx, const float* __restrict__ out_w,
           const float* __restrict__ out_b, float* __restrict__ out)
{
  __shared__ float ctxT[512][17];
  const int tid = threadIdx.x;
  const int b0 = (blockIdx.x & 1) * 16;
  const int v0 = (blockIdx.x >> 1) * 16;
  for (int i = tid; i < 16 * 128; i += 256) {
    const int bb = i & 15;
    const int k4 = (i >> 4) * 4;
    const float4 v = *(const float4*)(ctx + (size_t)(b0 + bb)*512 + k4);
    ctxT[k4+0][bb] = v.x; ctxT[k4+1][bb] = v.y;
    ctxT[k4+2][bb] = v.z; ctxT[k4+3][bb] = v.w;
  }
  __syncthreads();
  const int tx = tid & 15;
  const int ty = tid >> 4;
  const int v = v0 + ty;
  const int bb = b0 + tx;
  const float* wr = out_w + (size_t)v * 512;
  float acc = 0.f;
#pragma unroll 4
  for (int k = 0; k < 512; k += 4) {
    const float4 w4 = *(const float4*)(wr + k);
    acc = fmaf(w4.x, ctxT[k+0][tx], acc);
    acc = fmaf(w4.y, ctxT[k+1][tx], acc);
    acc = fmaf(w4.z, ctxT[k+2][tx], acc);
    acc = fmaf(w4.w, ctxT[k+3][tx], acc);
  }
  out[(size_t)bb * 32000 + v] = acc + out_b[v];
}

extern "C" void kernel_launch(void* const* d_in, const int* in_sizes, int n_in,
                              void* d_out, int out_size, void* d_ws, size_t ws_size,
                              hipStream_t stream)
{
  const int*   seq   = (const int*)d_in[0];
  const float* embed = (const float*)d_in[1];
  const float* w1    = (const float*)d_in[2];
  const float* b1    = (const float*)d_in[3];
  const float* w2    = (const float*)d_in[4];
  const float* b2    = (const float*)d_in[5];
  const float* ln_g  = (const float*)d_in[6];
  const float* ln_b  = (const float*)d_in[7];
  const float* wg_w  = (const float*)d_in[8];
  const float* wg_b  = (const float*)d_in[9];
  const float* q_w   = (const float*)d_in[10];
  const float* q_b   = (const float*)d_in[11];
  const float* out_w = (const float*)d_in[12];
  const float* out_b = (const float*)d_in[13];
  float* out = (float*)d_out;

  char* ws = (char*)d_ws;
  size_t off = 0;
  auto alloc = [&](size_t bytes) {
    void* p = ws + off;
    off += (bytes + 255) & ~(size_t)255;
    return p;
  };
  float* ff1    = (float*)alloc((size_t)32768 * 1024 * 4);  // 134 MB
  float* xbuf   = (float*)alloc((size_t)32768 * 512 * 4);   //  67 MB
  float* scores = (float*)alloc((size_t)32 * 1021 * 4);
  float* norms  = (float*)alloc((size_t)32 * 1021 * 4);
  int*   selidx = (int*)alloc((size_t)32 * 64 * 4);
  int*   selcnt = (int*)alloc((size_t)32 * 4);
  float* qbuf   = (float*)alloc((size_t)32 * 512 * 4);
  float* ctxb   = (float*)alloc((size_t)32 * 512 * 4);

  gemm_mfma<1,1,0><<<2048, 256, 0, stream>>>(embed, seq, w1, b1, nullptr, ff1,
                                             32768, 1024, 512);
  gemm_mfma<0,0,1><<<1024, 256, 0, stream>>>(ff1, seq, w2, b2, embed, xbuf,
                                             32768, 512, 1024);
  ln_k<<<8192, 256, 0, stream>>>(xbuf, ln_g, ln_b, 32768);
  score_k<<<8168, 256, 0, stream>>>(xbuf, wg_w, wg_b, scores, norms);
  select_k<<<32, 256, 0, stream>>>(xbuf, scores, norms, selidx, selcnt);
  q_k<<<4096, 256, 0, stream>>>(xbuf, q_w, q_b, qbuf);
  attn_k<<<32, 256, 0, stream>>>(xbuf, qbuf, selidx, selcnt, ctxb);
  out_k<<<4000, 256, 0, stream>>>(ctxb, out_w, out_b, out);
}

// Round 4
// 446.790 us; speedup vs baseline: 2.8848x; 1.0660x over previous
//
#include <hip/hip_runtime.h>
#include <math.h>

typedef unsigned short ushort_t;
typedef short bf16x8 __attribute__((ext_vector_type(8)));
typedef unsigned short u16x8 __attribute__((ext_vector_type(8)));
typedef float f32x4 __attribute__((ext_vector_type(4)));

__device__ __forceinline__ float wsum64(float v) {
#pragma unroll
  for (int off = 32; off > 0; off >>= 1) v += __shfl_xor(v, off, 64);
  return v;
}

__device__ __forceinline__ ushort_t f2bf(float x) {   // RNE f32->bf16
  unsigned u = __float_as_uint(x);
  return (ushort_t)((u + 0x7fffu + ((u >> 16) & 1u)) >> 16);
}
__device__ __forceinline__ float bf2f(ushort_t h) {
  return __uint_as_float(((unsigned)h) << 16);
}

__device__ __forceinline__ void split8(const float4 a, const float4 b,
                                       u16x8& h, u16x8& l) {
  h[0]=f2bf(a.x); l[0]=f2bf(a.x-bf2f(h[0]));
  h[1]=f2bf(a.y); l[1]=f2bf(a.y-bf2f(h[1]));
  h[2]=f2bf(a.z); l[2]=f2bf(a.z-bf2f(h[2]));
  h[3]=f2bf(a.w); l[3]=f2bf(a.w-bf2f(h[3]));
  h[4]=f2bf(b.x); l[4]=f2bf(b.x-bf2f(h[4]));
  h[5]=f2bf(b.y); l[5]=f2bf(b.y-bf2f(h[5]));
  h[6]=f2bf(b.z); l[6]=f2bf(b.z-bf2f(h[6]));
  h[7]=f2bf(b.w); l[7]=f2bf(b.w-bf2f(h[7]));
}

// async global(per-lane) -> LDS(wave-uniform base + lane*16B), 16B per lane
__device__ __forceinline__ void gl16(const void* g, const void* l) {
  __builtin_amdgcn_global_load_lds(
      (const __attribute__((address_space(1))) unsigned int*)g,
      (__attribute__((address_space(3))) unsigned int*)l, 16, 0, 0);
}

// ---------------------------------------------------------------------------
// gather-split: Ah/Al[row][512] bf16 hi/lo of embed[seq[row]]
// ---------------------------------------------------------------------------
__global__ __launch_bounds__(256)
void gather_split(const int* __restrict__ seq, const float* __restrict__ embed,
                  ushort_t* __restrict__ Ah, ushort_t* __restrict__ Al)
{
  const int wid = threadIdx.x >> 6, lane = threadIdx.x & 63;
  const int row = blockIdx.x * 4 + wid;
  const float* src = embed + (size_t)seq[row] * 512 + lane * 8;
  const float4 a = *(const float4*)src;
  const float4 b = *(const float4*)(src + 4);
  u16x8 h, l;
  split8(a, b, h, l);
  *(u16x8*)(Ah + (size_t)row * 512 + lane * 8) = h;
  *(u16x8*)(Al + (size_t)row * 512 + lane * 8) = l;
}

// elementwise weight split (n8 = total_elems/8)
__global__ __launch_bounds__(256)
void split_w(const float* __restrict__ W, ushort_t* __restrict__ Wh,
             ushort_t* __restrict__ Wl, int n8)
{
  const int i = blockIdx.x * 256 + threadIdx.x;
  if (i >= n8) return;
  const float4 a = *(const float4*)(W + (size_t)i * 8);
  const float4 b = *(const float4*)(W + (size_t)i * 8 + 4);
  u16x8 h, l;
  split8(a, b, h, l);
  *(u16x8*)(Wh + (size_t)i * 8) = h;
  *(u16x8*)(Wl + (size_t)i * 8) = l;
}

// ---------------------------------------------------------------------------
// Pre-split bf16 MFMA GEMM: C[m,n] = sum_k A[m,k]*B[n,k], A,B given as hi/lo
// bf16 pairs. 128x128 tile, BK=32, 4 waves (2x2), 4x4 16x16x32 frags, 3-term
// split MFMA. Staging via global_load_lds (16B) with XOR-chunk swizzle applied
// on the global source; double-buffered LDS, 1 barrier/iter (T3 min-2-phase).
// EPI 0: +bias, relu, store bf16 hi/lo.  EPI 1: +bias +embed[seq[row]] resid,
// store f32.
// ---------------------------------------------------------------------------
template<int EPI>
__global__ __launch_bounds__(256, 2)
void gemm_pre(const ushort_t* __restrict__ Ah, const ushort_t* __restrict__ Al,
              const ushort_t* __restrict__ Bh, const ushort_t* __restrict__ Bl,
              const float* __restrict__ bias,
              const int* __restrict__ seq, const float* __restrict__ embed,
              ushort_t* __restrict__ Oh, ushort_t* __restrict__ Ol,
              float* __restrict__ Of,
              int N, int K)
{
  __shared__ __align__(16) ushort_t lds[2 * 16384];   // 2 stages x 32KB
  const int tid = threadIdx.x;
  const int numN = N >> 7;
  int bid = blockIdx.x;
  {  // XCD-aware swizzle (grids are multiples of 8)
    const int chunk = gridDim.x >> 3;
    bid = (bid & 7) * chunk + (bid >> 3);
  }
  const int m0 = (bid / numN) << 7;
  const int n0 = (bid % numN) << 7;
  const int wid = tid >> 6, lane = tid & 63;
  const int wm = wid >> 1, wn = wid & 1;
  const int l16 = lane & 15, lkb = lane >> 4;

  // staging geometry: buffer = [128 rows][4 chunks of 16B]; LDS chunk (r,c)
  // holds global chunk (r, c ^ ((r>>1)&3)). Wave wid stages chunks
  // [wid*128, wid*128+128) of each buffer via 2 insts.
  const int j0 = wid * 128 + lane;
  const int r0 = j0 >> 2, sc0 = (j0 & 3) ^ ((r0 >> 1) & 3);
  const int j1 = j0 + 64;
  const int r1 = j1 >> 2, sc1 = (j1 & 3) ^ ((r1 >> 1) & 3);

  const ushort_t* pAh0 = Ah + (size_t)(m0 + r0) * K + sc0 * 8;
  const ushort_t* pAh1 = Ah + (size_t)(m0 + r1) * K + sc1 * 8;
  const ushort_t* pAl0 = Al + (size_t)(m0 + r0) * K + sc0 * 8;
  const ushort_t* pAl1 = Al + (size_t)(m0 + r1) * K + sc1 * 8;
  const ushort_t* pBh0 = Bh + (size_t)(n0 + r0) * K + sc0 * 8;
  const ushort_t* pBh1 = Bh + (size_t)(n0 + r1) * K + sc1 * 8;
  const ushort_t* pBl0 = Bl + (size_t)(n0 + r0) * K + sc0 * 8;
  const ushort_t* pBl1 = Bl + (size_t)(n0 + r1) * K + sc1 * 8;
  const int wo0 = wid * 1024, wo1 = wid * 1024 + 512;   // u16 offsets (wave-uniform)

  auto STAGE = [&](int k0, int s) {
    ushort_t* sb = lds + s * 16384;
    gl16(pAh0 + k0, sb + wo0);
    gl16(pAh1 + k0, sb + wo1);
    gl16(pAl0 + k0, sb + 4096 + wo0);
    gl16(pAl1 + k0, sb + 4096 + wo1);
    gl16(pBh0 + k0, sb + 8192 + wo0);
    gl16(pBh1 + k0, sb + 8192 + wo1);
    gl16(pBl0 + k0, sb + 12288 + wo0);
    gl16(pBl1 + k0, sb + 12288 + wo1);
  };

  f32x4 acc[4][4];
#pragma unroll
  for (int m = 0; m < 4; ++m)
#pragma unroll
    for (int n = 0; n < 4; ++n) acc[m][n] = (f32x4){0.f, 0.f, 0.f, 0.f};

  // fragment read offsets (u16): logical (row R, chunk lkb) lives at LDS
  // chunk lkb ^ ((R>>1)&3); (R>>1)&3 == (l16>>1)&3 for all m/n sub-tiles.
  const int swz = (l16 >> 1) & 3;
  const int ardA = (wm * 64 + l16) * 32 + ((lkb ^ swz) << 3);
  const int ardB = (wn * 64 + l16) * 32 + ((lkb ^ swz) << 3);

  STAGE(0, 0);
  __syncthreads();
  const int NT = K >> 5;
  for (int t = 0; t < NT; ++t) {
    if (t + 1 < NT) STAGE((t + 1) << 5, (t + 1) & 1);  // prefetch next stage
    const ushort_t* sb = lds + (t & 1) * 16384;
    bf16x8 fah[4], fal[4];
#pragma unroll
    for (int m = 0; m < 4; ++m) {
      fah[m] = *(const bf16x8*)(sb + ardA + m * 512);
      fal[m] = *(const bf16x8*)(sb + 4096 + ardA + m * 512);
    }
#pragma unroll
    for (int n = 0; n < 4; ++n) {
      const bf16x8 fbh = *(const bf16x8*)(sb + 8192 + ardB + n * 512);
      const bf16x8 fbl = *(const bf16x8*)(sb + 12288 + ardB + n * 512);
#pragma unroll
      for (int m = 0; m < 4; ++m) {
        acc[m][n] = __builtin_amdgcn_mfma_f32_16x16x32_bf16(fah[m], fbh, acc[m][n], 0, 0, 0);
        acc[m][n] = __builtin_amdgcn_mfma_f32_16x16x32_bf16(fal[m], fbh, acc[m][n], 0, 0, 0);
        acc[m][n] = __builtin_amdgcn_mfma_f32_16x16x32_bf16(fah[m], fbl, acc[m][n], 0, 0, 0);
      }
    }
    __syncthreads();   // drains vmcnt(0): next stage landed; all reads done
  }

  // epilogue: C/D frag layout col=lane&15, row=(lane>>4)*4+i
#pragma unroll
  for (int n = 0; n < 4; ++n) {
    const int col = n0 + wn * 64 + n * 16 + l16;
    const float bv = bias[col];
#pragma unroll
    for (int m = 0; m < 4; ++m) {
      const int rbase = m0 + wm * 64 + m * 16 + lkb * 4;
#pragma unroll
      for (int i = 0; i < 4; ++i) {
        const int row = rbase + i;
        float v = acc[m][n][i] + bv;
        if (EPI == 0) {
          v = fmaxf(v, 0.f);
          const ushort_t h = f2bf(v);
          Oh[(size_t)row * N + col] = h;
          Ol[(size_t)row * N + col] = f2bf(v - bf2f(h));
        } else {
          v += embed[(size_t)seq[row] * 512 + col];
          Of[(size_t)row * N + col] = v;
        }
      }
    }
  }
}

// in-place LayerNorm + fused gate score + L2 norm; one wave per 512-elem row
__global__ __launch_bounds__(256)
void lnscore_k(float* __restrict__ x, const float* __restrict__ g,
               const float* __restrict__ bt, const float* __restrict__ wg_w,
               const float* __restrict__ wg_b, float* __restrict__ scores,
               float* __restrict__ norms)
{
  const int wid = threadIdx.x >> 6, lane = threadIdx.x & 63;
  const int row = blockIdx.x * 4 + wid;
  float* xr = x + (size_t)row * 512;
  const float4 v0 = *(const float4*)(xr + lane*4);
  const float4 v1 = *(const float4*)(xr + 256 + lane*4);
  float s = v0.x+v0.y+v0.z+v0.w + v1.x+v1.y+v1.z+v1.w;
  s = wsum64(s);
  const float mu = s * (1.f/512.f);
  float ss = (v0.x-mu)*(v0.x-mu) + (v0.y-mu)*(v0.y-mu)
           + (v0.z-mu)*(v0.z-mu) + (v0.w-mu)*(v0.w-mu)
           + (v1.x-mu)*(v1.x-mu) + (v1.y-mu)*(v1.y-mu)
           + (v1.z-mu)*(v1.z-mu) + (v1.w-mu)*(v1.w-mu);
  ss = wsum64(ss);
  const float inv = 1.f / sqrtf(ss * (1.f/512.f) + 1e-5f);
  const float4 g0 = *(const float4*)(g + lane*4);
  const float4 g1 = *(const float4*)(g + 256 + lane*4);
  const float4 c0 = *(const float4*)(bt + lane*4);
  const float4 c1 = *(const float4*)(bt + 256 + lane*4);
  float4 o0, o1;
  o0.x = (v0.x-mu)*inv*g0.x + c0.x;  o0.y = (v0.y-mu)*inv*g0.y + c0.y;
  o0.z = (v0.z-mu)*inv*g0.z + c0.z;  o0.w = (v0.w-mu)*inv*g0.w + c0.w;
  o1.x = (v1.x-mu)*inv*g1.x + c1.x;  o1.y = (v1.y-mu)*inv*g1.y + c1.y;
  o1.z = (v1.z-mu)*inv*g1.z + c1.z;  o1.w = (v1.w-mu)*inv*g1.w + c1.w;
  *(float4*)(xr + lane*4) = o0;
  *(float4*)(xr + 256 + lane*4) = o1;

  // fused score + norm (candidates only)
  const float4 q0 = *(const float4*)(wg_w + lane*4);
  const float4 q1 = *(const float4*)(wg_w + 256 + lane*4);
  float d = o0.x*q0.x + o0.y*q0.y + o0.z*q0.z + o0.w*q0.w
          + o1.x*q1.x + o1.y*q1.y + o1.z*q1.z + o1.w*q1.w;
  float n2 = o0.x*o0.x + o0.y*o0.y + o0.z*o0.z + o0.w*o0.w
           + o1.x*o1.x + o1.y*o1.y + o1.z*o1.z + o1.w*o1.w;
  d = wsum64(d); n2 = wsum64(n2);
  const int b = row >> 10, t = row & 1023;
  if (lane == 0 && t < 1021) {
    scores[b * 1021 + t] = d + wg_b[0];
    norms[b * 1021 + t] = sqrtf(n2);
  }
}

// ---------------------------------------------------------------------------
// Greedy score-ranked selection with cosine dedup; one block per batch row.
// ---------------------------------------------------------------------------
__global__ __launch_bounds__(256, 1)
void select_k(const float* __restrict__ hidden, const float* __restrict__ scores,
              const float* __restrict__ norms, int* __restrict__ selidx_g,
              int* __restrict__ selcnt_g)
{
  __shared__ __align__(16) ushort_t allH[128 * 520];     // 133120 B (keys alias)
  __shared__ ushort_t simS[64 * 128];
  __shared__ ushort_t sortedIdx[1024];
  __shared__ ushort_t selT[64];
  __shared__ ushort_t newPos[64];
  __shared__ int s_count, s_nacc;

  const int b = blockIdx.x, tid = threadIdx.x;
  const int wid = tid >> 6, lane = tid & 63;
  const int l16 = lane & 15, lkb = lane >> 4;

  // ---- phase 1: bitonic argsort by (-score, idx), stable
  unsigned long long* keys = (unsigned long long*)allH;
  for (int i = tid; i < 1024; i += 256) {
    const float s = (i < 1021) ? scores[b * 1021 + i] : -INFINITY;
    const unsigned u = __float_as_uint(s);
    const unsigned ms = (u & 0x80000000u) ? ~u : (u | 0x80000000u);
    keys[i] = ((unsigned long long)(~ms) << 32) | (unsigned)i;
  }
  __syncthreads();
  for (int k = 2; k <= 1024; k <<= 1) {
    for (int j = k >> 1; j > 0; j >>= 1) {
      for (int i = tid; i < 1024; i += 256) {
        const int ixj = i ^ j;
        if (ixj > i) {
          const unsigned long long a = keys[i], c = keys[ixj];
          const bool up = ((i & k) == 0);
          if ((a > c) == up) { keys[i] = c; keys[ixj] = a; }
        }
      }
      __syncthreads();
    }
  }
  for (int i = tid; i < 1024; i += 256)
    sortedIdx[i] = (ushort_t)(keys[i] & 0xffffu);
  if (tid == 0) s_count = 0;
  __syncthreads();

  // ---- phase 2: chunked greedy NMS
  int p = 0;
  while (true) {
    const int count = s_count;
    if (count >= 64 || p >= 1021) break;
    const int C = min(64, 1021 - p);

    {
      const int r = tid >> 2;
      const int seg = (tid & 3) * 128;
      if (r < C) {
        const int t = sortedIdx[p + r];
        const float rn = 1.f / fmaxf(norms[b * 1021 + t], 1e-12f);
        const float* src = hidden + ((size_t)b * 1024 + t) * 512 + seg;
        ushort_t* dst = allH + (64 + r) * 520 + seg;
#pragma unroll
        for (int u0 = 0; u0 < 128; u0 += 8) {
          const float4 x = *(const float4*)(src + u0);
          const float4 y = *(const float4*)(src + u0 + 4);
          u16x8 o;
          o[0] = f2bf(x.x * rn); o[1] = f2bf(x.y * rn);
          o[2] = f2bf(x.z * rn); o[3] = f2bf(x.w * rn);
          o[4] = f2bf(y.x * rn); o[5] = f2bf(y.y * rn);
          o[6] = f2bf(y.z * rn); o[7] = f2bf(y.w * rn);
          *(u16x8*)(dst + u0) = o;
        }
      }
    }
    __syncthreads();

    {
      f32x4 acc[8];
#pragma unroll
      for (int t = 0; t < 8; ++t) acc[t] = (f32x4){0.f, 0.f, 0.f, 0.f};
      const ushort_t* Abase = allH + (64 + (wid << 4) + l16) * 520;
#pragma unroll
      for (int ks = 0; ks < 16; ++ks) {
        const bf16x8 a = *(const bf16x8*)(Abase + ks * 32 + lkb * 8);
#pragma unroll
        for (int t = 0; t < 8; ++t) {
          const bf16x8 bb = *(const bf16x8*)(allH + ((t << 4) + l16) * 520 + ks * 32 + lkb * 8);
          acc[t] = __builtin_amdgcn_mfma_f32_16x16x32_bf16(a, bb, acc[t], 0, 0, 0);
        }
      }
#pragma unroll
      for (int t = 0; t < 8; ++t)
#pragma unroll
        for (int ii = 0; ii < 4; ++ii) {
          const int ri = (wid << 4) + lkb * 4 + ii;
          simS[ri * 128 + (t << 4) + l16] = f2bf(acc[t][ii]);
        }
    }
    __syncthreads();

    if (wid == 0) {
      unsigned long long accMask = 0ull;
      int nacc = 0;
      for (int i = 0; i < C; ++i) {
        float v = -INFINITY;
        if (lane < count) v = bf2f(simS[i * 128 + lane]);
        if ((accMask >> lane) & 1ull) v = fmaxf(v, bf2f(simS[i * 128 + 64 + lane]));
#pragma unroll
        for (int off = 32; off > 0; off >>= 1) v = fmaxf(v, __shfl_xor(v, off, 64));
        const int total = count + nacc;
        const bool ok = (total == 0) || (v <= 0.8f);
        if (total < 64 && ok) {
          if (lane == 0) { selT[total] = sortedIdx[p + i]; newPos[nacc] = (ushort_t)i; }
          accMask |= (1ull << i);
          ++nacc;
          if (total + 1 == 64) break;
        }
      }
      if (lane == 0) { s_nacc = nacc; s_count = count + nacc; }
    }
    __syncthreads();

    {
      const int nacc = s_nacc;
      for (int a = wid; a < nacc; a += 4) {
        const int srcrow = 64 + (int)newPos[a];
        const int dstrow = count + a;
        const u16x8 val = *(const u16x8*)(allH + srcrow * 520 + lane * 8);
        *(u16x8*)(allH + dstrow * 520 + lane * 8) = val;
      }
    }
    p += C;
    __syncthreads();
  }

  __syncthreads();
  if (tid < 64) selidx_g[b * 64 + tid] = (tid < s_count) ? (int)selT[tid] : 0;
  if (tid == 0) selcnt_g[b] = s_count;
}

// q = hidden[:, T-2, :] @ q_w^T + q_b ; one wave per output element
__global__ __launch_bounds__(256)
void q_k(const float* __restrict__ hidden, const float* __restrict__ q_w,
         const float* __restrict__ q_b, float* __restrict__ qv)
{
  const int wid = threadIdx.x >> 6, lane = threadIdx.x & 63;
  const int o = blockIdx.x * 4 + wid;
  const int b = o >> 9, n = o & 511;
  const float* hr = hidden + ((size_t)b*1024 + 1022) * 512;
  const float* wr = q_w + (size_t)n * 512;
  const float4 h0 = *(const float4*)(hr + lane*4);
  const float4 h1 = *(const float4*)(hr + 256 + lane*4);
  const float4 w0 = *(const float4*)(wr + lane*4);
  const float4 w1 = *(const float4*)(wr + 256 + lane*4);
  float d = h0.x*w0.x + h0.y*w0.y + h0.z*w0.z + h0.w*w0.w
          + h1.x*w1.x + h1.y*w1.y + h1.z*w1.z + h1.w*w1.w;
  d = wsum64(d);
  if (lane == 0) qv[o] = d + q_b[n];
}

// masked softmax attention over selected memory; one block per batch
__global__ __launch_bounds__(256)
void attn_k(const float* __restrict__ hidden, const float* __restrict__ qv,
            const int* __restrict__ selidx_g, const int* __restrict__ selcnt_g,
            float* __restrict__ ctx)
{
  const int b = blockIdx.x, tid = threadIdx.x;
  const int wid = tid >> 6, lane = tid & 63;
  __shared__ float qs[512];
  __shared__ int sidx[64];
  __shared__ float sv[64];
  __shared__ float av[64];
  const int count = selcnt_g[b];
  for (int i = tid; i < 512; i += 256) qs[i] = qv[b*512 + i];
  if (tid < 64) sidx[tid] = selidx_g[b*64 + tid];
  __syncthreads();
  for (int m = wid; m < 64; m += 4) {
    float sval = -1e9f;
    if (m < count) {
      const float* hr = hidden + ((size_t)b*1024 + sidx[m]) * 512;
      const float4 a0 = *(const float4*)(hr + lane*4);
      const float4 a1 = *(const float4*)(hr + 256 + lane*4);
      const float4 q0 = *(const float4*)(&qs[lane*4]);
      const float4 q1 = *(const float4*)(&qs[256 + lane*4]);
      float d = a0.x*q0.x + a0.y*q0.y + a0.z*q0.z + a0.w*q0.w
              + a1.x*q1.x + a1.y*q1.y + a1.z*q1.z + a1.w*q1.w;
      d = wsum64(d);
      sval = d;
    }
    if (lane == 0) sv[m] = sval;
  }
  __syncthreads();
  if (tid < 64) {
    const float v = sv[tid];
    float mx = v;
#pragma unroll
    for (int off = 32; off > 0; off >>= 1) mx = fmaxf(mx, __shfl_xor(mx, off, 64));
    const float e = expf(v - mx);
    float ssum = e;
#pragma unroll
    for (int off = 32; off > 0; off >>= 1) ssum += __shfl_xor(ssum, off, 64);
    av[tid] = e / ssum;
  }
  __syncthreads();
  for (int n = tid; n < 512; n += 256) {
    float a = 0.f;
    for (int m = 0; m < count; ++m)
      a += av[m] * hidden[((size_t)b*1024 + sidx[m]) * 512 + n];
    ctx[b*512 + n] = a;
  }
}

// out = ctx @ out_w^T + out_b ; 16 vocab rows x 16 batches per block
__global__ __launch_bounds__(256)
void out_k(const float* __restrict__ ctx, const float* __restrict__ out_w,
           const float* __restrict__ out_b, float* __restrict__ out)
{
  __shared__ float ctxT[512][17];
  const int tid = threadIdx.x;
  const int b0 = (blockIdx.x & 1) * 16;
  const int v0 = (blockIdx.x >> 1) * 16;
  for (int i = tid; i < 16 * 128; i += 256) {
    const int bb = i & 15;
    const int k4 = (i >> 4) * 4;
    const float4 v = *(const float4*)(ctx + (size_t)(b0 + bb)*512 + k4);
    ctxT[k4+0][bb] = v.x; ctxT[k4+1][bb] = v.y;
    ctxT[k4+2][bb] = v.z; ctxT[k4+3][bb] = v.w;
  }
  __syncthreads();
  const int tx = tid & 15;
  const int ty = tid >> 4;
  const int v = v0 + ty;
  const int bb = b0 + tx;
  const float* wr = out_w + (size_t)v * 512;
  float acc = 0.f;
#pragma unroll 4
  for (int k = 0; k < 512; k += 4) {
    const float4 w4 = *(const float4*)(wr + k);
    acc = fmaf(w4.x, ctxT[k+0][tx], acc);
    acc = fmaf(w4.y, ctxT[k+1][tx], acc);
    acc = fmaf(w4.z, ctxT[k+2][tx], acc);
    acc = fmaf(w4.w, ctxT[k+3][tx], acc);
  }
  out[(size_t)bb * 32000 + v] = acc + out_b[v];
}

extern "C" void kernel_launch(void* const* d_in, const int* in_sizes, int n_in,
                              void* d_out, int out_size, void* d_ws, size_t ws_size,
                              hipStream_t stream)
{
  const int*   seq   = (const int*)d_in[0];
  const float* embed = (const float*)d_in[1];
  const float* w1    = (const float*)d_in[2];
  const float* b1    = (const float*)d_in[3];
  const float* w2    = (const float*)d_in[4];
  const float* b2    = (const float*)d_in[5];
  const float* ln_g  = (const float*)d_in[6];
  const float* ln_b  = (const float*)d_in[7];
  const float* wg_w  = (const float*)d_in[8];
  const float* wg_b  = (const float*)d_in[9];
  const float* q_w   = (const float*)d_in[10];
  const float* q_b   = (const float*)d_in[11];
  const float* out_w = (const float*)d_in[12];
  const float* out_b = (const float*)d_in[13];
  float* out = (float*)d_out;

  char* ws = (char*)d_ws;
  size_t off = 0;
  auto alloc = [&](size_t bytes) {
    void* p = ws + off;
    off += (bytes + 255) & ~(size_t)255;
    return p;
  };
  // Ahid/Alid (pre-split gathered hidden input) alias xbuf: Ahid/Alid are dead
  // once FF1 finishes; FF2 writes xbuf (f32) over the same region.
  void* xA = alloc((size_t)32768 * 512 * 4);            // 67 MB
  ushort_t* Ahid = (ushort_t*)xA;
  ushort_t* Alid = Ahid + (size_t)32768 * 512;
  float* xbuf = (float*)xA;
  ushort_t* ff1h = (ushort_t*)alloc((size_t)32768 * 1024 * 2);  // 67 MB
  ushort_t* ff1l = (ushort_t*)alloc((size_t)32768 * 1024 * 2);  // 67 MB
  ushort_t* w1h = (ushort_t*)alloc((size_t)1024 * 512 * 2);
  ushort_t* w1l = (ushort_t*)alloc((size_t)1024 * 512 * 2);
  ushort_t* w2h = (ushort_t*)alloc((size_t)512 * 1024 * 2);
  ushort_t* w2l = (ushort_t*)alloc((size_t)512 * 1024 * 2);
  float* scores = (float*)alloc((size_t)32 * 1021 * 4);
  float* norms  = (float*)alloc((size_t)32 * 1021 * 4);
  int*   selidx = (int*)alloc((size_t)32 * 64 * 4);
  int*   selcnt = (int*)alloc((size_t)32 * 4);
  float* qbuf   = (float*)alloc((size_t)32 * 512 * 4);
  float* ctxb   = (float*)alloc((size_t)32 * 512 * 4);

  // pre-split passes
  gather_split<<<8192, 256, 0, stream>>>(seq, embed, Ahid, Alid);
  split_w<<<256, 256, 0, stream>>>(w1, w1h, w1l, 65536);
  split_w<<<256, 256, 0, stream>>>(w2, w2h, w2l, 65536);

  // FF1: relu(h @ w1^T + b1) -> ff1 hi/lo bf16   [32768,1024]
  gemm_pre<0><<<2048, 256, 0, stream>>>(Ahid, Alid, w1h, w1l, b1,
                                        nullptr, nullptr, ff1h, ff1l, nullptr,
                                        1024, 512);
  // FF2: ff1 @ w2^T + b2 + embed[seq] -> xbuf f32 [32768,512]
  gemm_pre<1><<<1024, 256, 0, stream>>>(ff1h, ff1l, w2h, w2l, b2,
                                        seq, embed, nullptr, nullptr, xbuf,
                                        512, 1024);
  // LayerNorm in place + fused scores/norms
  lnscore_k<<<8192, 256, 0, stream>>>(xbuf, ln_g, ln_b, wg_w, wg_b, scores, norms);
  // greedy dedup selection
  select_k<<<32, 256, 0, stream>>>(xbuf, scores, norms, selidx, selcnt);
  // q projection for query row (t = 1022)
  q_k<<<4096, 256, 0, stream>>>(xbuf, q_w, q_b, qbuf);
  // attention over selected memory -> ctx
  attn_k<<<32, 256, 0, stream>>>(xbuf, qbuf, selidx, selcnt, ctxb);
  // final vocab projection
  out_k<<<4000, 256, 0, stream>>>(ctxb, out_w, out_b, out);
}